// Round 1
// 49.041 us; speedup vs baseline: 1.2286x; 1.2286x over previous
//
#include <hip/hip_runtime.h>
#include <climits>
#include <math.h>

#define N_NODES 100000
#define N_EGO   8192
#define N_EDGES 1600000
#define HIDDEN  128
#define MID     64
#define OUT_D   16
#define CAP     96                       // per-ego neighbor cap; P(deg>=96) ~ 1e-44
#define BM_WORDS ((N_NODES + 31) / 32)   // 12.5KB ego bitmap, L1-resident
#define NR      2                        // node ranges (u8 LDS histogram)
#define RSZ     50000                    // nodes per range
#define RWORDS  (RSZ / 4)                // 12500 u32 words = 50KB LDS
#define BPR     128                      // blocks (edge slices) per range
#define SLICE   (N_EDGES / BPR)          // 12500 edges per block
#define S4TOT   (SLICE / 4)              // 3125 int4s per slice
#define EPW     4                        // egos per wave in k_mlp

// ---------------- weight folding (linearity of conv∘lin1) -------------------
// mid[m] = relu( s4·F[:,m] + t*G[m] + C[m] ),  s4 = Σ_e norm_e x_e  (4 floats)
// F[d][m] = Σ_k convW[d][k] w1[k][m]   (4x64)
// G[m]    = w1[128][m]                 (time row)
// C[m]    = b1[m] + Σ_k convB[k] w1[k][m]
// W2T[o][m] = w2[m][o]                 (16x64, for coalesced lin2 reads)
__device__ __forceinline__ void fold_weights(
        int blk, int t,
        const float* __restrict__ convW, const float* __restrict__ convB,
        const float* __restrict__ w1, const float* __restrict__ b1,
        const float* __restrict__ w2,
        float* __restrict__ F, float* __restrict__ G,
        float* __restrict__ C, float* __restrict__ W2T) {
    if (blk == 0) {
        const int d = t >> 6, m = t & 63;          // 256 threads -> 4x64
        float acc = 0.f;
        for (int k = 0; k < HIDDEN; ++k)
            acc = fmaf(convW[d * HIDDEN + k], w1[k * MID + m], acc);
        F[d * MID + m] = acc;
        if (d == 0) {
            float c = b1[m];
            for (int k = 0; k < HIDDEN; ++k)
                c = fmaf(convB[k], w1[k * MID + m], c);
            C[m] = c;
            G[m] = w1[HIDDEN * MID + m];
        }
    } else if (blk == 1) {
        for (int i2 = t; i2 < OUT_D * MID; i2 += 256) {
            int o = i2 >> 6, m = i2 & 63;
            W2T[i2] = w2[m * OUT_D + o];
        }
    }
}

// ---------------- fast path: u8-packed LDS histogram ------------------------

__global__ void k_init(int* __restrict__ rep, unsigned* __restrict__ cnt,
                       unsigned* __restrict__ bitmap,
                       const float* __restrict__ convW, const float* __restrict__ convB,
                       const float* __restrict__ w1, const float* __restrict__ b1,
                       const float* __restrict__ w2,
                       float* __restrict__ F, float* __restrict__ G,
                       float* __restrict__ C, float* __restrict__ W2T) {
    int i = blockIdx.x * blockDim.x + threadIdx.x;
    if (i < N_NODES)  rep[i] = INT_MAX;
    if (i < N_EGO)    cnt[i] = 0u;
    if (i < BM_WORDS) bitmap[i] = 0u;
    fold_weights(blockIdx.x, threadIdx.x, convW, convB, w1, b1, w2, F, G, C, W2T);
}

__global__ void k_rep(const int* __restrict__ ego_idx, int* __restrict__ rep,
                      unsigned* __restrict__ bitmap) {
    int i = blockIdx.x * blockDim.x + threadIdx.x;
    if (i < N_EGO) {
        int node = ego_idx[i];
        atomicMin(&rep[node], i);
        atomicOr(&bitmap[node >> 5], 1u << (node & 31));
    }
}

__global__ __launch_bounds__(1024, 8) void k_hist(
        const int* __restrict__ srcp, const int* __restrict__ dstp,
        const unsigned* __restrict__ bitmap, const int* __restrict__ rep,
        unsigned* __restrict__ cnt, int* __restrict__ list,
        unsigned* __restrict__ partials) {
    __shared__ unsigned h[RWORDS];              // 50KB, four u8 counters/word
    const int r = blockIdx.x >> 7;              // node range 0..1
    const int b = blockIdx.x & (BPR - 1);       // edge slice 0..127
    for (int i = threadIdx.x; i < RWORDS; i += 1024) h[i] = 0u;
    __syncthreads();

    const int lo    = r * RSZ;
    const int ebase = b * SLICE;
    // balanced split of the 3125 int4s: r=0 -> [0,1562), r=1 -> [1562,3125)
    const int slo = (r * S4TOT) / NR;
    const int shi = ((r + 1) * S4TOT) / NR;
    const int4* dp = reinterpret_cast<const int4*>(dstp + ebase);
    const int4* sp = reinterpret_cast<const int4*>(srcp + ebase);

    for (int i = threadIdx.x; i < S4TOT; i += 1024) {
        const int4 d = dp[i];
        const int dv[4] = {d.x, d.y, d.z, d.w};
        const bool sc = (i >= slo) & (i < shi);
        int sv[4] = {0, 0, 0, 0};
        if (sc) {                                // coalesced src stream, half slice
            const int4 s = sp[i];
            sv[0] = s.x; sv[1] = s.y; sv[2] = s.z; sv[3] = s.w;
        }
        #pragma unroll
        for (int k = 0; k < 4; ++k) {
            // u8-packed histogram; per-block per-node mean 0.125, max ~8 << 255
            unsigned a = (unsigned)(dv[k] - lo);
            if (a < RSZ) atomicAdd(&h[a >> 2], 1u << (8 * (a & 3)));
            if (sc) {
                int dd = dv[k];
                if ((bitmap[(unsigned)dd >> 5] >> (dd & 31)) & 1u) {   // ~8% pass
                    int rr = rep[dd];
                    unsigned pos = atomicAdd(&cnt[rr], 1u);
                    if (pos < CAP) list[rr * CAP + pos] = sv[k];
                }
            }
        }
    }
    __syncthreads();

    unsigned* outp = partials + (size_t)blockIdx.x * RWORDS;
    for (int j = threadIdx.x; j < RWORDS; j += 1024) outp[j] = h[j];
}

__global__ void k_red(const unsigned* __restrict__ partials,
                      float* __restrict__ dinv) {
    int j = blockIdx.x * blockDim.x + threadIdx.x;   // u32 word = 4 nodes
    if (j >= N_NODES / 4) return;
    int n0 = 4 * j;
    int r  = n0 / RSZ;
    int w  = (n0 - r * RSZ) >> 2;
    const unsigned* base = partials + (size_t)(r * BPR) * RWORDS + w;
    unsigned s02 = 0, s13 = 0;                   // SWAR: max 128*255 < 65536
    #pragma unroll 8
    for (int bb = 0; bb < BPR; ++bb) {
        unsigned v = base[(size_t)bb * RWORDS];
        s02 += v & 0x00FF00FFu;
        s13 += (v >> 8) & 0x00FF00FFu;
    }
    float4 o;
    o.x = rsqrtf((float)((s02 & 0xFFFFu) + 1u));   // +1 self-loop
    o.y = rsqrtf((float)((s13 & 0xFFFFu) + 1u));
    o.z = rsqrtf((float)((s02 >> 16) + 1u));
    o.w = rsqrtf((float)((s13 >> 16) + 1u));
    reinterpret_cast<float4*>(dinv)[j] = o;
}

// ---------------- fallback path: device-scope atomics (proven) --------------

__global__ void k_init_fb(unsigned* __restrict__ deg, int* __restrict__ rep,
                          unsigned* __restrict__ cnt, unsigned* __restrict__ bitmap,
                          const float* __restrict__ convW, const float* __restrict__ convB,
                          const float* __restrict__ w1, const float* __restrict__ b1,
                          const float* __restrict__ w2,
                          float* __restrict__ F, float* __restrict__ G,
                          float* __restrict__ C, float* __restrict__ W2T) {
    int i = blockIdx.x * blockDim.x + threadIdx.x;
    if (i < N_NODES)  { deg[i] = 1u; rep[i] = INT_MAX; }
    if (i < N_EGO)    cnt[i] = 0u;
    if (i < BM_WORDS) bitmap[i] = 0u;
    fold_weights(blockIdx.x, threadIdx.x, convW, convB, w1, b1, w2, F, G, C, W2T);
}

__global__ __launch_bounds__(256) void k_edge_fb(
        const int* __restrict__ srcp, const int* __restrict__ dstp,
        unsigned* __restrict__ deg, const int* __restrict__ rep,
        const unsigned* __restrict__ bitmap,
        unsigned* __restrict__ cnt, int* __restrict__ list) {
    int t = blockIdx.x * blockDim.x + threadIdx.x;
    if (t * 4 >= N_EDGES) return;
    const int4 d4 = reinterpret_cast<const int4*>(dstp)[t];
    const int4 s4 = reinterpret_cast<const int4*>(srcp)[t];
    const int dv[4] = {d4.x, d4.y, d4.z, d4.w};
    const int sv[4] = {s4.x, s4.y, s4.z, s4.w};
    unsigned bm[4];
    #pragma unroll
    for (int k = 0; k < 4; ++k) {
        atomicAdd(&deg[dv[k]], 1u);
        bm[k] = bitmap[(unsigned)dv[k] >> 5];
    }
    #pragma unroll
    for (int k = 0; k < 4; ++k) {
        if ((bm[k] >> (dv[k] & 31)) & 1u) {
            int r = rep[dv[k]];
            unsigned pos = atomicAdd(&cnt[r], 1u);
            if (pos < CAP) list[r * CAP + pos] = sv[k];
        }
    }
}

__global__ void k_dinv_fb(const unsigned* __restrict__ deg, float* __restrict__ dinv) {
    int i = blockIdx.x * blockDim.x + threadIdx.x;
    if (i < N_NODES) dinv[i] = rsqrtf((float)deg[i]);
}

// ---------------- epilogue: 4-float gather + folded MLP ---------------------
// per wave: 4 egos; 16 lanes/ego gather Σ dinv[s]*x[s] (shuffle-reduced),
// then mid = relu(s4·F + t·G + C) (4 outputs/lane), LDS b128 round-trip,
// lin2 via W2T b128 reads. ~18 LDS instrs + ~28 VMEM per wave (vs ~260 LDS before).

__global__ __launch_bounds__(64) void k_mlp(
    const float* __restrict__ data1, const float* __restrict__ ego_time,
    const int* __restrict__ ego_idx,
    const float* __restrict__ F, const float* __restrict__ G,
    const float* __restrict__ C, const float* __restrict__ W2T,
    const float* __restrict__ b2,
    const int* __restrict__ rep, const unsigned* __restrict__ cnt,
    const int* __restrict__ list, const float* __restrict__ dinv,
    float* __restrict__ out) {
    __shared__ float mid_s[EPW][MID];
    const int lane = threadIdx.x;
    const int e    = lane >> 4;               // ego within wave 0..3
    const int sl   = lane & 15;               // slot within ego group
    const int i    = blockIdx.x * EPW + e;    // ego id (grid = N_EGO/EPW exact)
    const int node = ego_idx[i];
    const int r    = rep[node];
    int n = (int)cnt[r]; if (n > CAP) n = CAP;
    const float dvd = dinv[node];
    const int* lrow = list + (size_t)r * CAP;

    // s4_inner = Σ_neighbors dinv[s]*x[s]  (+ dvd*x[node] self term)
    float px = 0.f, py = 0.f, pz = 0.f, pw = 0.f;
    for (int k = sl; k < n; k += 16) {
        int s = lrow[k];
        float w = dinv[s];
        float4 x = reinterpret_cast<const float4*>(data1)[s];
        px = fmaf(w, x.x, px); py = fmaf(w, x.y, py);
        pz = fmaf(w, x.z, pz); pw = fmaf(w, x.w, pw);
    }
    if (sl == 15) {
        float4 x = reinterpret_cast<const float4*>(data1)[node];
        px = fmaf(dvd, x.x, px); py = fmaf(dvd, x.y, py);
        pz = fmaf(dvd, x.z, pz); pw = fmaf(dvd, x.w, pw);
    }
    #pragma unroll
    for (int m = 1; m <= 8; m <<= 1) {        // butterfly within 16-lane group
        px += __shfl_xor(px, m);
        py += __shfl_xor(py, m);
        pz += __shfl_xor(pz, m);
        pw += __shfl_xor(pw, m);
    }
    const float sx = dvd * px, sy = dvd * py, sz = dvd * pz, sw = dvd * pw;
    const float t  = ego_time[i];

    // mid[m] for m = sl*4 .. sl*4+3
    const float4 f0 = reinterpret_cast<const float4*>(F)[0 * 16 + sl];
    const float4 f1 = reinterpret_cast<const float4*>(F)[1 * 16 + sl];
    const float4 f2 = reinterpret_cast<const float4*>(F)[2 * 16 + sl];
    const float4 f3 = reinterpret_cast<const float4*>(F)[3 * 16 + sl];
    const float4 g  = reinterpret_cast<const float4*>(G)[sl];
    const float4 c  = reinterpret_cast<const float4*>(C)[sl];
    float4 mid;
    mid.x = fmaxf(fmaf(sx, f0.x, fmaf(sy, f1.x, fmaf(sz, f2.x, fmaf(sw, f3.x, fmaf(t, g.x, c.x))))), 0.f);
    mid.y = fmaxf(fmaf(sx, f0.y, fmaf(sy, f1.y, fmaf(sz, f2.y, fmaf(sw, f3.y, fmaf(t, g.y, c.y))))), 0.f);
    mid.z = fmaxf(fmaf(sx, f0.z, fmaf(sy, f1.z, fmaf(sz, f2.z, fmaf(sw, f3.z, fmaf(t, g.z, c.z))))), 0.f);
    mid.w = fmaxf(fmaf(sx, f0.w, fmaf(sy, f1.w, fmaf(sz, f2.w, fmaf(sw, f3.w, fmaf(t, g.w, c.w))))), 0.f);
    reinterpret_cast<float4*>(mid_s[e])[sl] = mid;
    __syncthreads();

    // lin2: lane -> output o = sl of ego e
    float acc = b2[sl];
    const float4* m4 = reinterpret_cast<const float4*>(mid_s[e]);
    const float4* w4 = reinterpret_cast<const float4*>(W2T + sl * MID);
    #pragma unroll
    for (int q = 0; q < 16; ++q) {
        float4 mm = m4[q]; float4 ww = w4[q];
        acc = fmaf(mm.x, ww.x, acc); acc = fmaf(mm.y, ww.y, acc);
        acc = fmaf(mm.z, ww.z, acc); acc = fmaf(mm.w, ww.w, acc);
    }
    out[(size_t)i * OUT_D + sl] = 1.0f / (1.0f + expf(-acc));
}

extern "C" void kernel_launch(void* const* d_in, const int* in_sizes, int n_in,
                              void* d_out, int out_size, void* d_ws, size_t ws_size,
                              hipStream_t stream) {
    const float* data1    = (const float*)d_in[0];
    const int*   edge     = (const int*)d_in[1];   // [2, N_EDGES] int32
    const float* ego_time = (const float*)d_in[2];
    const int*   ego_idx  = (const int*)d_in[3];
    const float* convW    = (const float*)d_in[4];
    const float* convB    = (const float*)d_in[5];
    const float* w1       = (const float*)d_in[6];
    const float* b1       = (const float*)d_in[7];
    const float* w2       = (const float*)d_in[8];
    const float* b2       = (const float*)d_in[9];
    float* out = (float*)d_out;

    char* ws = (char*)d_ws;
    size_t off = 0;
    auto alloc = [&](size_t b) { size_t p = off; off += (b + 511) & ~(size_t)511; return p; };
    int*      rep    = (int*)     (ws + alloc((size_t)N_NODES * 4));
    unsigned* bitmap = (unsigned*)(ws + alloc((size_t)BM_WORDS * 4));
    unsigned* cnt    = (unsigned*)(ws + alloc((size_t)N_EGO * 4));
    float*    dinv   = (float*)   (ws + alloc((size_t)N_NODES * 4));
    float*    F      = (float*)   (ws + alloc((size_t)4 * MID * 4));
    float*    G      = (float*)   (ws + alloc((size_t)MID * 4));
    float*    C      = (float*)   (ws + alloc((size_t)MID * 4));
    float*    W2T    = (float*)   (ws + alloc((size_t)OUT_D * MID * 4));
    int*      list   = (int*)     (ws + alloc((size_t)N_EGO * CAP * 4));
    size_t tail = off;   // path-specific region
    unsigned* partials = (unsigned*)(ws + tail);            // NR*BPR*50KB = 12.8MB
    unsigned* deg      = (unsigned*)(ws + tail);            // 400KB (fallback)
    const size_t need_hist = tail + (size_t)NR * BPR * RWORDS * 4 + 512;
    const size_t need_fb   = tail + (size_t)N_NODES * 4 + 512;

    const int* srcp = edge;
    const int* dstp = edge + N_EDGES;

    if (ws_size >= need_hist) {
        hipLaunchKernelGGL(k_init, dim3((N_NODES + 255) / 256), dim3(256), 0, stream,
                           rep, cnt, bitmap, convW, convB, w1, b1, w2, F, G, C, W2T);
        hipLaunchKernelGGL(k_rep, dim3((N_EGO + 255) / 256), dim3(256), 0, stream,
                           ego_idx, rep, bitmap);
        hipLaunchKernelGGL(k_hist, dim3(NR * BPR), dim3(1024), 0, stream,
                           srcp, dstp, bitmap, rep, cnt, list, partials);
        hipLaunchKernelGGL(k_red, dim3((N_NODES / 4 + 255) / 256), dim3(256), 0, stream,
                           partials, dinv);
    } else if (ws_size >= need_fb) {
        hipLaunchKernelGGL(k_init_fb, dim3((N_NODES + 255) / 256), dim3(256), 0, stream,
                           deg, rep, cnt, bitmap, convW, convB, w1, b1, w2, F, G, C, W2T);
        hipLaunchKernelGGL(k_rep, dim3((N_EGO + 255) / 256), dim3(256), 0, stream,
                           ego_idx, rep, bitmap);
        hipLaunchKernelGGL(k_edge_fb, dim3((N_EDGES / 4 + 255) / 256), dim3(256), 0, stream,
                           srcp, dstp, deg, rep, bitmap, cnt, list);
        hipLaunchKernelGGL(k_dinv_fb, dim3((N_NODES + 255) / 256), dim3(256), 0, stream,
                           deg, dinv);
    }
    hipLaunchKernelGGL(k_mlp, dim3(N_EGO / EPW), dim3(64), 0, stream,
                       data1, ego_time, ego_idx, F, G, C, W2T, b2,
                       rep, cnt, list, dinv, out);
}